// Round 1
// baseline (79.757 us; speedup 1.0000x reference)
//
#include <hip/hip_runtime.h>
#include <hip/hip_bf16.h>

#define N_TOTAL 8192
#define B_HALF  4096
#define D       256
#define BM      128
#define BK      64

typedef __bf16 bf16x8v __attribute__((ext_vector_type(8)));
typedef float  f32x4v  __attribute__((ext_vector_type(4)));

__device__ __forceinline__ unsigned short f2bf(float x) {
    unsigned int u = __float_as_uint(x);
    unsigned int r = (u + 0x7FFFu + ((u >> 16) & 1u)) >> 16;
    return (unsigned short)r;
}
__device__ __forceinline__ float bf2f(unsigned short b) {
    return __uint_as_float(((unsigned int)b) << 16);
}

__device__ __forceinline__ void gload_lds16(const void* g, void* l) {
    __builtin_amdgcn_global_load_lds(
        (const __attribute__((address_space(1))) unsigned int*)g,
        (__attribute__((address_space(3))) unsigned int*)l,
        16, 0, 0);
}

// ---------------------------------------------------------------------------
// prep: f32 -> bf16 (workspace), row norms sq[] (from the bf16 values, so the
// Gram diagonal matches exactly), column sums s[] and sum of sq (f64) for the
// closed-form bandwidth.
// One block = 32 rows; 4 waves x 8 rows; lane holds 4 consecutive columns.
// ---------------------------------------------------------------------------
__global__ void prep_kernel(const float* __restrict__ src,
                            const float* __restrict__ tgt,
                            unsigned short* __restrict__ tb,
                            float* __restrict__ sq,
                            float* __restrict__ s,
                            double* __restrict__ sumsq) {
    __shared__ float colpart[4][256];
    int tid = threadIdx.x;
    int wv = tid >> 6, ln = tid & 63;
    int row0 = blockIdx.x * 32 + wv * 8;

    float cp0 = 0.f, cp1 = 0.f, cp2 = 0.f, cp3 = 0.f;
    double dsum = 0.0;

    for (int t = 0; t < 8; ++t) {
        int row = row0 + t;
        const float* p = (row < B_HALF) ? (src + (size_t)row * D)
                                        : (tgt + (size_t)(row - B_HALF) * D);
        float4 v = *(const float4*)(p + ln * 4);
        unsigned short b0 = f2bf(v.x), b1 = f2bf(v.y), b2 = f2bf(v.z), b3 = f2bf(v.w);
        float x0 = bf2f(b0), x1 = bf2f(b1), x2 = bf2f(b2), x3 = bf2f(b3);
        ushort4 u; u.x = b0; u.y = b1; u.z = b2; u.w = b3;
        *(ushort4*)(tb + (size_t)row * D + ln * 4) = u;

        cp0 += x0; cp1 += x1; cp2 += x2; cp3 += x3;

        float sqp = x0 * x0 + x1 * x1 + x2 * x2 + x3 * x3;
        #pragma unroll
        for (int off = 32; off; off >>= 1) sqp += __shfl_down(sqp, off, 64);
        if (ln == 0) { sq[row] = sqp; dsum += (double)sqp; }
    }
    colpart[wv][ln * 4 + 0] = cp0;
    colpart[wv][ln * 4 + 1] = cp1;
    colpart[wv][ln * 4 + 2] = cp2;
    colpart[wv][ln * 4 + 3] = cp3;
    __syncthreads();
    float cs = colpart[0][tid] + colpart[1][tid] + colpart[2][tid] + colpart[3][tid];
    atomicAdd(&s[tid], cs);
    if (ln == 0) atomicAdd(sumsq, dsum);
}

// ---------------------------------------------------------------------------
// bandwidth:  sum(L2) = 2n*sum(sq) - 2*||sum_i x_i||^2 ;  bw = sumL2/(n^2-n)
// store cexp = log2(e)/(16*bw) so that e0 = exp2(-L2*cexp) = exp(-L2/(16 bw))
// ---------------------------------------------------------------------------
__global__ void bw_kernel(const float* __restrict__ s,
                          const double* __restrict__ sumsq,
                          float* __restrict__ cexp) {
    __shared__ double red[256];
    int t = threadIdx.x;
    float v = s[t];
    red[t] = (double)v * (double)v;
    __syncthreads();
    for (int off = 128; off; off >>= 1) {
        if (t < off) red[t] += red[t + off];
        __syncthreads();
    }
    if (t == 0) {
        double sl2 = 2.0 * (double)N_TOTAL * sumsq[0] - 2.0 * red[0];
        double bw = sl2 / ((double)N_TOTAL * N_TOTAL - (double)N_TOTAL);
        cexp[0] = (float)(1.4426950408889634 / (16.0 * bw));
    }
}

// ---------------------------------------------------------------------------
// main: lower-triangular 128x128 tiles of the Gram matrix via bf16 MFMA,
// fused L2 -> exp2 -> 5-kernel sum -> signed reduction.
// 256 threads = 4 waves (2x2), each wave a 64x64 quadrant = 4x4 16x16 frags.
// ---------------------------------------------------------------------------
__global__ void mmd_kernel(const unsigned short* __restrict__ tb,
                           const float* __restrict__ sq,
                           const float* __restrict__ cexp_p,
                           double* __restrict__ acc_out) {
    __shared__ __align__(16) unsigned short ldsA[BM * BK];  // 16 KB
    __shared__ __align__(16) unsigned short ldsB[BM * BK];  // 16 KB
    __shared__ float sqi[BM], sqj[BM];
    __shared__ float redbuf[4];

    // triangle decode: block t -> (r,c), r >= c
    int t = blockIdx.x;
    int r = (int)((sqrtf(8.0f * (float)t + 1.0f) - 1.0f) * 0.5f);
    while ((r + 1) * (r + 2) / 2 <= t) ++r;
    while (r * (r + 1) / 2 > t) --r;
    int c = t - r * (r + 1) / 2;
    int rowBase = r * BM, colBase = c * BM;

    int tid = threadIdx.x;
    int wv = tid >> 6, ln = tid & 63;
    int wr = wv >> 1, wc = wv & 1;

    if (tid < BM) sqi[tid] = sq[rowBase + tid];
    else          sqj[tid - BM] = sq[colBase + (tid - BM)];
    float cexp = cexp_p[0];

    f32x4v acc[4][4] = {};

    for (int ks = 0; ks < D / BK; ++ks) {
        int kb0 = ks * BK;
        // stage A and B tiles (16 KB each) via global_load_lds width 16.
        // linear LDS byte offset o = i*4096 + wv*1024 + ln*16 ;
        // row = o/128 (BK*2 bytes per row), colb = o%128.
        #pragma unroll
        for (int i = 0; i < 4; ++i) {
            int o = i * 4096 + wv * 1024 + ln * 16;
            int rowl = o >> 7;
            int colb = o & 127;
            const unsigned short* gA =
                tb + (size_t)(rowBase + rowl) * D + kb0 + (colb >> 1);
            gload_lds16(gA, (char*)ldsA + i * 4096 + wv * 1024);
            const unsigned short* gB =
                tb + (size_t)(colBase + rowl) * D + kb0 + (colb >> 1);
            gload_lds16(gB, (char*)ldsB + i * 4096 + wv * 1024);
        }
        asm volatile("s_waitcnt vmcnt(0)" ::: "memory");
        __syncthreads();

        #pragma unroll
        for (int kk = 0; kk < 2; ++kk) {
            bf16x8v a[4], b[4];
            #pragma unroll
            for (int mi = 0; mi < 4; ++mi) {
                int rowl = wr * 64 + mi * 16 + (ln & 15);
                int colb = (kk * 32 + (ln >> 4) * 8) * 2;
                a[mi] = *(const bf16x8v*)((const char*)ldsA + rowl * 128 + colb);
            }
            #pragma unroll
            for (int ni = 0; ni < 4; ++ni) {
                int rowl = wc * 64 + ni * 16 + (ln & 15);
                int colb = (kk * 32 + (ln >> 4) * 8) * 2;
                b[ni] = *(const bf16x8v*)((const char*)ldsB + rowl * 128 + colb);
            }
            #pragma unroll
            for (int mi = 0; mi < 4; ++mi)
                #pragma unroll
                for (int ni = 0; ni < 4; ++ni)
                    acc[mi][ni] = __builtin_amdgcn_mfma_f32_16x16x32_bf16(
                        a[mi], b[ni], acc[mi][ni], 0, 0, 0);
        }
        __syncthreads();
    }

    // epilogue: L2 = sq_i + sq_j - 2*gram ; 5 kernels = e0+e0^2+e0^4+e0^8+e0^16
    // C/D layout (16x16x32): col = lane&15, row = (lane>>4)*4 + reg
    float tacc = 0.f;
    #pragma unroll
    for (int mi = 0; mi < 4; ++mi) {
        #pragma unroll
        for (int ni = 0; ni < 4; ++ni) {
            int jl = wc * 64 + ni * 16 + (ln & 15);
            float sqjv = sqj[jl];
            int jglob = colBase + jl;
            bool jS = jglob < B_HALF;
            #pragma unroll
            for (int rg = 0; rg < 4; ++rg) {
                int il = wr * 64 + mi * 16 + (ln >> 4) * 4 + rg;
                float sqiv = sqi[il];
                int iglob = rowBase + il;
                float sgn = ((iglob < B_HALF) == jS) ? 1.f : -1.f;
                float L2 = sqiv + sqjv - 2.0f * acc[mi][ni][rg];
                float e0 = __builtin_amdgcn_exp2f(-L2 * cexp);
                float e2 = e0 * e0, e4 = e2 * e2, e8 = e4 * e4, e16 = e8 * e8;
                tacc += sgn * (e0 + e2 + e4 + e8 + e16);
            }
        }
    }
    if (r != c) tacc *= 2.f;  // off-diagonal tile counts for (r,c) and (c,r)

    #pragma unroll
    for (int off = 32; off; off >>= 1) tacc += __shfl_down(tacc, off, 64);
    if (ln == 0) redbuf[wv] = tacc;
    __syncthreads();
    if (tid == 0) {
        float bsum = redbuf[0] + redbuf[1] + redbuf[2] + redbuf[3];
        atomicAdd(acc_out, (double)bsum);
    }
}

__global__ void final_kernel(const double* __restrict__ acc,
                             float* __restrict__ out) {
    if (threadIdx.x == 0)
        out[0] = (float)(acc[0] / (5.0 * (double)B_HALF * (double)B_HALF));
}

// ---------------------------------------------------------------------------
extern "C" void kernel_launch(void* const* d_in, const int* in_sizes, int n_in,
                              void* d_out, int out_size, void* d_ws, size_t ws_size,
                              hipStream_t stream) {
    const float* src = (const float*)d_in[0];
    const float* tgt = (const float*)d_in[1];
    float* out = (float*)d_out;
    char* ws = (char*)d_ws;

    double* sumsq = (double*)(ws + 0);
    double* acc   = (double*)(ws + 8);
    float*  cexp  = (float*)(ws + 16);
    float*  s     = (float*)(ws + 64);     // 256 f32
    float*  sq    = (float*)(ws + 4096);   // 8192 f32
    unsigned short* tb = (unsigned short*)(ws + 65536);  // 8192*256 bf16 = 4 MB

    // zero the accumulators (ws is poisoned 0xAA and not re-poisoned between
    // replays -> must re-init every call)
    hipMemsetAsync(ws, 0, 2048, stream);

    prep_kernel<<<N_TOTAL / 32, 256, 0, stream>>>(src, tgt, tb, sq, s, sumsq);
    bw_kernel<<<1, 256, 0, stream>>>(s, sumsq, cexp);

    int ntiles = (N_TOTAL / BM);                 // 64
    int nblocks = ntiles * (ntiles + 1) / 2;     // 2080
    mmd_kernel<<<nblocks, 256, 0, stream>>>(tb, sq, cexp, acc);
    final_kernel<<<1, 64, 0, stream>>>(acc, out);
}